// Round 7
// baseline (492.762 us; speedup 1.0000x reference)
//
#include <hip/hip_runtime.h>

// EdgeConv fused pipeline, MI355X gfx950 — round 7.
// R6 post-mortem: pass2 occupancy 29% == exactly the (256,3) launch-bound cap;
// VGPR only 68. Latency-bound gather needs resident waves, not per-wave ILP.
// R7: (a) pass1 (256,6), pass2 (256,5) — occupancy ceilings 75%/62%;
// (b) merge pack_w+cvt into one prep kernel; fold finalize1/finalize2 into
// the heads of pass2/pass3 (per-block redundant recompute from 16-slot gacc);
// (c) 4 kernels total + 16KB memset. Structure of R6 otherwise unchanged.

#define N_NODES 100000
#define KE 16
#define E_EDGES (N_NODES * KE)
#define BN_EPS 1e-5f
#define NCHUNK (N_NODES / KE)      // 6250 16-node block-chunks (exact)
#define GSLOTS 16

typedef __attribute__((ext_vector_type(8))) short bf16x8;  // 8 bf16 (4 VGPRs)
typedef __attribute__((ext_vector_type(4))) float f32x4;   // MFMA C/D
typedef __attribute__((ext_vector_type(4))) int i32x4;

#define MFMA(a, b, c) __builtin_amdgcn_mfma_f32_16x16x32_bf16((a), (b), (c), 0, 0, 0)

static __device__ __forceinline__ short bf16b(float f) {
  __bf16 h = (__bf16)f;  // RNE, hardware cvt on gfx950
  return __builtin_bit_cast(short, h);
}

#if __has_builtin(__builtin_amdgcn_cvt_pk_bf16_f32)
static __device__ __forceinline__ int pk2(float a, float b) {
  return __builtin_bit_cast(int, __builtin_amdgcn_cvt_pk_bf16_f32(a, b));
}
#else
static __device__ __forceinline__ int pk2(float a, float b) {
  return (int)(unsigned short)bf16b(a) | ((int)(unsigned short)bf16b(b) << 16);
}
#endif

static __device__ __forceinline__ bf16x8 pack8(float4 a, float4 b) {
  i32x4 v = {pk2(a.x, a.y), pk2(a.z, a.w), pk2(b.x, b.y), pk2(b.z, b.w)};
  return __builtin_bit_cast(bf16x8, v);
}

static __device__ __forceinline__ float bf2f(short s) {
  unsigned u = ((unsigned)(unsigned short)s) << 16;
  return __builtin_bit_cast(float, u);
}

// ---- prep: x -> bf16 (blocks < 3125) + weight packing (blocks 3125..3130) --
// wp[(s*4+t)*64 + l] holds 8 bf16: B[k=32s + (l>>4)*8 + j][c=16t + (l&15)]
// Weight split: k-steps 0,1 (xi) get Wd = W1[:64]-W1[64:]; k-steps 2,3 (xj)
// get Wb = W1[64:] — removes the xj-xi subtraction from the hot loops.
__global__ __launch_bounds__(256) void k_prep(const float* __restrict__ x,
                                              short* __restrict__ xb,
                                              const float* __restrict__ W1,
                                              const float* __restrict__ W2,
                                              short* __restrict__ wp1,
                                              short* __restrict__ wp2) {
  if (blockIdx.x < 3125) {
    int g = blockIdx.x * 256 + threadIdx.x;  // 800000 threads, 8 elems each
    const float4* x4 = (const float4*)x;
    float4 f0 = x4[2 * g], f1 = x4[2 * g + 1];
    *(bf16x8*)(xb + g * 8) = pack8(f0, f1);
    return;
  }
  int tid = (blockIdx.x - 3125) * 256 + threadIdx.x;
  if (tid < 1024) {
    int l = tid & 63, st = tid >> 6;
    int s = st >> 2, t = st & 3;
    int quad = l >> 4, n16 = l & 15;
    for (int j = 0; j < 8; j++) {
      int k = 32 * s + quad * 8 + j, c = 16 * t + n16;
      float w = (s < 2) ? (W1[k * 64 + c] - W1[(k + 64) * 64 + c])
                        : W1[k * 64 + c];
      wp1[tid * 8 + j] = bf16b(w);
    }
  } else if (tid < 1536) {
    int e = tid - 1024;
    int l = e & 63, st = e >> 6;
    int s = st >> 2, t = st & 3;
    int quad = l >> 4, n16 = l & 15;
    for (int j = 0; j < 8; j++) {
      int k = 32 * s + quad * 8 + j, c = 16 * t + n16;
      wp2[e * 8 + j] = bf16b(W2[k * 64 + c]);
    }
  }
}

// ---- stats helpers ---------------------------------------------------------
static __device__ __forceinline__ void stat_acc(const f32x4 acc[4], float sacc[4],
                                                float qacc[4]) {
#pragma unroll
  for (int t = 0; t < 4; t++) {
    sacc[t] += (acc[t][0] + acc[t][1]) + (acc[t][2] + acc[t][3]);
    qacc[t] = fmaf(acc[t][0], acc[t][0],
              fmaf(acc[t][1], acc[t][1],
              fmaf(acc[t][2], acc[t][2],
              fmaf(acc[t][3], acc[t][3], qacc[t]))));
  }
}

static __device__ __forceinline__ void stat_flush(float sacc[4], float qacc[4],
                                                  int quad, int n16, float* lstat) {
#pragma unroll
  for (int t = 0; t < 4; t++) {
    float s = sacc[t], q = qacc[t];
    s += __shfl_xor(s, 16); s += __shfl_xor(s, 32);
    q += __shfl_xor(q, 16); q += __shfl_xor(q, 32);
    if (quad == 0) {
      atomicAdd(&lstat[16 * t + n16], s);
      atomicAdd(&lstat[64 + 16 * t + n16], q);
    }
  }
}

// folded BN finalize: per-block recompute of bn coeffs from the 16-slot gacc
static __device__ __forceinline__ void bn_finalize(const float* __restrict__ gacc,
                                                   const float* __restrict__ g,
                                                   const float* __restrict__ be,
                                                   float* lbn, int tid) {
  if (tid < 64) {
    float s = 0.f, q = 0.f;
#pragma unroll
    for (int i = 0; i < GSLOTS; i++) {
      s += gacc[i * 128 + tid];
      q += gacc[i * 128 + 64 + tid];
    }
    float mean = s * (1.0f / E_EDGES);
    float var = q * (1.0f / E_EDGES) - mean * mean;  // biased, matches ref
    float rstd = rsqrtf(var + BN_EPS);
    float a = g[tid] * rstd;
    lbn[tid] = a;
    lbn[64 + tid] = be[tid] - mean * a;  // bn(v) = v*a + b
  }
}

// ---- pass 1: 4-nodes-per-wave gather + GEMM1 + stats1 ----------------------
__global__ __launch_bounds__(256, 6) void k_pass1(const short* __restrict__ xb,
                                                  const int* __restrict__ ecol,
                                                  const bf16x8* __restrict__ wp1,
                                                  float* __restrict__ gacc) {
  __shared__ float lstat[128];
  __shared__ int eblk[256];
  __shared__ __align__(16) short xit[1024];     // 16 xi rows (2 KB)
  __shared__ __align__(16) short wfl[8192];     // W1 B-frags (16 KB)
  int tid = threadIdx.x;
  if (tid < 128) lstat[tid] = 0.f;
  int nb = blockIdx.x * 16;
  eblk[tid] = ecol[nb * KE + tid];              // 256 indices, coalesced
  if (tid < 128)
    *(bf16x8*)(&xit[tid * 8]) = ((const bf16x8*)(xb + (size_t)nb * 64))[tid];
#pragma unroll
  for (int r = 0; r < 4; r++)                   // 16 KB W1 frags -> LDS
    ((bf16x8*)wfl)[r * 256 + tid] = wp1[r * 256 + tid];
  __syncthreads();
  int wave = tid >> 6, l = tid & 63, quad = l >> 4, n16 = l & 15;
  const bf16x8* wf = (const bf16x8*)wfl;
  // all 8 gather loads up-front: 4 nodes x 2 x 16B per lane, static regs
  bf16x8 j0[4], j1[4];
#pragma unroll
  for (int v = 0; v < 4; v++) {
    int idx = eblk[(wave * 4 + v) * 16 + n16];
    const short* pj = xb + (size_t)idx * 64 + quad * 8;
    j0[v] = *(const bf16x8*)pj;
    j1[v] = *(const bf16x8*)(pj + 32);
  }
  float sacc[4] = {0.f, 0.f, 0.f, 0.f}, qacc[4] = {0.f, 0.f, 0.f, 0.f};
#pragma unroll
  for (int v = 0; v < 4; v++) {
    int p = wave * 4 + v;
    bf16x8 xi0 = *(const bf16x8*)(&xit[p * 64 + quad * 8]);
    bf16x8 xi1 = *(const bf16x8*)(&xit[p * 64 + 32 + quad * 8]);
    f32x4 acc[4];
#pragma unroll
    for (int t = 0; t < 4; t++) {
      f32x4 a = {0.f, 0.f, 0.f, 0.f};
      a = MFMA(xi0, wf[(0 + t) * 64 + l], a);
      a = MFMA(xi1, wf[(4 + t) * 64 + l], a);
      a = MFMA(j0[v], wf[(8 + t) * 64 + l], a);
      a = MFMA(j1[v], wf[(12 + t) * 64 + l], a);
      acc[t] = a;
    }
    stat_acc(acc, sacc, qacc);
  }
  stat_flush(sacc, qacc, quad, n16, lstat);
  __syncthreads();
  if (tid < 128)
    atomicAdd(&gacc[(blockIdx.x & (GSLOTS - 1)) * 128 + tid], lstat[tid]);
}

// ---- pass 2: gather + GEMM1 + BN1/ReLU + GEMM2 + stats2 + node min/max -----
__global__ __launch_bounds__(256, 5) void k_pass2(const short* __restrict__ xb,
                                                  const int* __restrict__ ecol,
                                                  const bf16x8* __restrict__ wp1,
                                                  const bf16x8* __restrict__ wp2,
                                                  const float* __restrict__ gacc1,
                                                  const float* __restrict__ g1,
                                                  const float* __restrict__ be1,
                                                  float* __restrict__ gacc,
                                                  short* __restrict__ hmax,
                                                  short* __restrict__ hmin) {
  __shared__ float lstat[128];
  __shared__ float lbn[128];
  __shared__ int eblk[256];
  __shared__ __align__(16) short xit[1024];
  __shared__ __align__(16) short wfl[8192];          // W1 B-frags (16 KB)
  __shared__ __align__(16) short tiles[4][16 * 72];  // per-wave D->A transpose
  int tid = threadIdx.x;
  if (tid < 128) lstat[tid] = 0.f;
  bn_finalize(gacc1, g1, be1, lbn, tid);             // folded finalize1
  int nb = blockIdx.x * 16;
  eblk[tid] = ecol[nb * KE + tid];
  if (tid < 128)
    *(bf16x8*)(&xit[tid * 8]) = ((const bf16x8*)(xb + (size_t)nb * 64))[tid];
#pragma unroll
  for (int r = 0; r < 4; r++)
    ((bf16x8*)wfl)[r * 256 + tid] = wp1[r * 256 + tid];
  __syncthreads();
  int wave = tid >> 6, l = tid & 63, quad = l >> 4, n16 = l & 15;
  const bf16x8* wf = (const bf16x8*)wfl;
  bf16x8 wf2[8];
#pragma unroll
  for (int u = 0; u < 8; u++) wf2[u] = wp2[u * 64 + l];
  float a1c[4], b1c[4];
#pragma unroll
  for (int t = 0; t < 4; t++) {
    a1c[t] = lbn[16 * t + n16];
    b1c[t] = lbn[64 + 16 * t + n16];
  }
  bf16x8 j0[4], j1[4];
#pragma unroll
  for (int v = 0; v < 4; v++) {
    int idx = eblk[(wave * 4 + v) * 16 + n16];
    const short* pj = xb + (size_t)idx * 64 + quad * 8;
    j0[v] = *(const bf16x8*)pj;
    j1[v] = *(const bf16x8*)(pj + 32);
  }
  float sacc[4] = {0.f, 0.f, 0.f, 0.f}, qacc[4] = {0.f, 0.f, 0.f, 0.f};
  short* myt = &tiles[wave][0];
#pragma unroll
  for (int v = 0; v < 4; v++) {
    int p = wave * 4 + v;
    bf16x8 xi0 = *(const bf16x8*)(&xit[p * 64 + quad * 8]);
    bf16x8 xi1 = *(const bf16x8*)(&xit[p * 64 + 32 + quad * 8]);
    f32x4 acc1[4];
#pragma unroll
    for (int t = 0; t < 4; t++) {
      f32x4 a = {0.f, 0.f, 0.f, 0.f};
      a = MFMA(xi0, wf[(0 + t) * 64 + l], a);
      a = MFMA(xi1, wf[(4 + t) * 64 + l], a);
      a = MFMA(j0[v], wf[(8 + t) * 64 + l], a);
      a = MFMA(j1[v], wf[(12 + t) * 64 + l], a);
      acc1[t] = a;
    }
    // BN1 + ReLU, D-layout -> row-major bf16 tile (per-wave, no barrier)
#pragma unroll
    for (int t = 0; t < 4; t++) {
      int c = 16 * t + n16;
#pragma unroll
      for (int r = 0; r < 4; r++) {
        float h = fmaxf(fmaf(acc1[t][r], a1c[t], b1c[t]), 0.f);
        myt[(quad * 4 + r) * 72 + c] = bf16b(h);
      }
    }
    bf16x8 f0 = *(bf16x8*)(myt + n16 * 72 + quad * 8);
    bf16x8 f1 = *(bf16x8*)(myt + n16 * 72 + 32 + quad * 8);
    f32x4 acc2[4];
#pragma unroll
    for (int t = 0; t < 4; t++) {
      f32x4 a = {0.f, 0.f, 0.f, 0.f};
      a = MFMA(f0, wf2[0 + t], a);
      a = MFMA(f1, wf2[4 + t], a);
      acc2[t] = a;
    }
    stat_acc(acc2, sacc, qacc);
    // per-node, per-channel max & min of h2_pre over the 16 edges
    float vmx[4], vmn[4];
#pragma unroll
    for (int t = 0; t < 4; t++) {
      float mx = fmaxf(fmaxf(acc2[t][0], acc2[t][1]), fmaxf(acc2[t][2], acc2[t][3]));
      float mn = fminf(fminf(acc2[t][0], acc2[t][1]), fminf(acc2[t][2], acc2[t][3]));
      mx = fmaxf(mx, __shfl_xor(mx, 16)); mx = fmaxf(mx, __shfl_xor(mx, 32));
      mn = fminf(mn, __shfl_xor(mn, 16)); mn = fminf(mn, __shfl_xor(mn, 32));
      vmx[t] = mx; vmn[t] = mn;
    }
    int n = nb + p;
    float ox = (quad == 0) ? vmx[0] : (quad == 1) ? vmx[1] : (quad == 2) ? vmx[2] : vmx[3];
    float on = (quad == 0) ? vmn[0] : (quad == 1) ? vmn[1] : (quad == 2) ? vmn[2] : vmn[3];
    hmax[(size_t)n * 64 + l] = bf16b(ox);  // lane l == channel l: coalesced
    hmin[(size_t)n * 64 + l] = bf16b(on);
  }
  stat_flush(sacc, qacc, quad, n16, lstat);
  __syncthreads();
  if (tid < 128)
    atomicAdd(&gacc[(blockIdx.x & (GSLOTS - 1)) * 128 + tid], lstat[tid]);
}

// ---- pass 3: folded finalize2 + elementwise BN2/ReLU + min/max select ------
// max_m relu(a*h+b) = relu(a>=0 ? a*hmax+b : a*hmin+b)  (affine+relu monotone)
__global__ __launch_bounds__(256) void k_pass3(const short* __restrict__ hmax,
                                               const short* __restrict__ hmin,
                                               const float* __restrict__ gacc2,
                                               const float* __restrict__ g2,
                                               const float* __restrict__ be2,
                                               float* __restrict__ out) {
  __shared__ float lbn[128];
  int tid = threadIdx.x;
  bn_finalize(gacc2, g2, be2, lbn, tid);  // folded finalize2
  __syncthreads();
  int g = blockIdx.x * 256 + tid;  // 1.6M threads, 4 channels each
  int base = g * 4;
  int c4 = base & 63;
  short4 mx4 = *(const short4*)(hmax + base);
  short4 mn4 = *(const short4*)(hmin + base);
  float4 a4 = *(const float4*)(&lbn[c4]);
  float4 b4 = *(const float4*)(&lbn[64 + c4]);
  float4 o;
  o.x = fmaxf(a4.x >= 0.f ? fmaf(a4.x, bf2f(mx4.x), b4.x) : fmaf(a4.x, bf2f(mn4.x), b4.x), 0.f);
  o.y = fmaxf(a4.y >= 0.f ? fmaf(a4.y, bf2f(mx4.y), b4.y) : fmaf(a4.y, bf2f(mn4.y), b4.y), 0.f);
  o.z = fmaxf(a4.z >= 0.f ? fmaf(a4.z, bf2f(mx4.z), b4.z) : fmaf(a4.z, bf2f(mn4.z), b4.z), 0.f);
  o.w = fmaxf(a4.w >= 0.f ? fmaf(a4.w, bf2f(mx4.w), b4.w) : fmaf(a4.w, bf2f(mn4.w), b4.w), 0.f);
  *(float4*)(out + base) = o;
}

extern "C" void kernel_launch(void* const* d_in, const int* in_sizes, int n_in,
                              void* d_out, int out_size, void* d_ws, size_t ws_size,
                              hipStream_t stream) {
  const float* x   = (const float*)d_in[0];
  // d_in[1] = edge_row: structurally repeat(arange(N),16), unused
  const int*   ec  = (const int*)d_in[2];
  const float* W1  = (const float*)d_in[3];
  // d_in[4] = b1: cancels in BN, unused
  const float* g1  = (const float*)d_in[5];
  const float* be1 = (const float*)d_in[6];
  const float* W2  = (const float*)d_in[7];
  // d_in[8] = b2: cancels in BN, unused
  const float* g2  = (const float*)d_in[9];
  const float* be2 = (const float*)d_in[10];
  float* out = (float*)d_out;

  char* ws = (char*)d_ws;
  bf16x8* wp1  = (bf16x8*)(ws);                 // 16 KB packed W1 (split)
  bf16x8* wp2  = (bf16x8*)(ws + 16384);         // 8 KB packed W2
  float* gacc1 = (float*)(ws + 24576);          // 16 slots x 128 = 8 KB
  float* gacc2 = (float*)(ws + 32768);          // 8 KB
  short* xb    = (short*)(ws + 98304);          // x in bf16: 12.8 MB
  short* hmax  = (short*)(ws + 98304 + 12800000);         // 12.8 MB
  short* hmin  = (short*)(ws + 98304 + 2 * 12800000);     // 12.8 MB

  // ws is re-poisoned to 0xAA before every launch: zero the stat accumulators
  hipMemsetAsync(gacc1, 0, 16384, stream);

  hipLaunchKernelGGL(k_prep, dim3(3131), dim3(256), 0, stream, x, xb,
                     W1, W2, (short*)wp1, (short*)wp2);
  hipLaunchKernelGGL(k_pass1, dim3(NCHUNK), dim3(256), 0, stream,
                     xb, ec, wp1, gacc1);
  hipLaunchKernelGGL(k_pass2, dim3(NCHUNK), dim3(256), 0, stream,
                     xb, ec, wp1, wp2, gacc1, g1, be1, gacc2, hmax, hmin);
  hipLaunchKernelGGL(k_pass3, dim3(6250), dim3(256), 0, stream,
                     hmax, hmin, gacc2, g2, be2, out);
}

// Round 8
// 221.965 us; speedup vs baseline: 2.2200x; 2.2200x over previous
//
#include <hip/hip_runtime.h>

// EdgeConv fused pipeline, MI355X gfx950 — round 8.
// R7 post-mortem: (256,6)/(256,5) launch bounds -> VGPR cap ~85 -> compiler
// spilled gather staging to scratch (FETCH 452MB + WRITE 547MB = 1GB spill
// traffic, 223us). Spill cliff >> occupancy gain. Revert to (256,4).
// R8 new: shared-xi GEMM — xi@Wd is identical for all 16 edges of a node, so
// wave0 computes Y=Xi@Wd once per 16-node block (8 MFMAs) into LDS; edge
// tiles init their accumulators from Y via broadcast ds_read_b32. GEMM1 per
// node: 16->8 MFMAs, wf LDS reads halved, xi ds_read_b128 eliminated.
// gacc zeroing folded into k_prep (no memset launch).

#define N_NODES 100000
#define KE 16
#define E_EDGES (N_NODES * KE)
#define BN_EPS 1e-5f
#define NCHUNK (N_NODES / KE)      // 6250 16-node block-chunks (exact)
#define GSLOTS 16

typedef __attribute__((ext_vector_type(8))) short bf16x8;  // 8 bf16 (4 VGPRs)
typedef __attribute__((ext_vector_type(4))) float f32x4;   // MFMA C/D
typedef __attribute__((ext_vector_type(4))) int i32x4;

#define MFMA(a, b, c) __builtin_amdgcn_mfma_f32_16x16x32_bf16((a), (b), (c), 0, 0, 0)

static __device__ __forceinline__ short bf16b(float f) {
  __bf16 h = (__bf16)f;  // RNE, hardware cvt on gfx950
  return __builtin_bit_cast(short, h);
}

#if __has_builtin(__builtin_amdgcn_cvt_pk_bf16_f32)
static __device__ __forceinline__ int pk2(float a, float b) {
  return __builtin_bit_cast(int, __builtin_amdgcn_cvt_pk_bf16_f32(a, b));
}
#else
static __device__ __forceinline__ int pk2(float a, float b) {
  return (int)(unsigned short)bf16b(a) | ((int)(unsigned short)bf16b(b) << 16);
}
#endif

static __device__ __forceinline__ bf16x8 pack8(float4 a, float4 b) {
  i32x4 v = {pk2(a.x, a.y), pk2(a.z, a.w), pk2(b.x, b.y), pk2(b.z, b.w)};
  return __builtin_bit_cast(bf16x8, v);
}

static __device__ __forceinline__ float bf2f(short s) {
  unsigned u = ((unsigned)(unsigned short)s) << 16;
  return __builtin_bit_cast(float, u);
}

// ---- prep: x->bf16 + weight packing + gacc zeroing (one kernel) ------------
// wp[(s*4+t)*64 + l] holds 8 bf16: B[k=32s + (l>>4)*8 + j][c=16t + (l&15)]
// Weight split: k-steps 0,1 (xi) get Wd = W1[:64]-W1[64:]; k-steps 2,3 (xj)
// get Wb = W1[64:] — removes the xj-xi subtraction from the hot loops.
__global__ __launch_bounds__(256) void k_prep(const float* __restrict__ x,
                                              short* __restrict__ xb,
                                              const float* __restrict__ W1,
                                              const float* __restrict__ W2,
                                              short* __restrict__ wp1,
                                              short* __restrict__ wp2,
                                              float* __restrict__ gaccz) {
  if (blockIdx.x < 3125) {
    int g = blockIdx.x * 256 + threadIdx.x;  // 800000 threads, 8 elems each
    const float4* x4 = (const float4*)x;
    float4 f0 = x4[2 * g], f1 = x4[2 * g + 1];
    *(bf16x8*)(xb + g * 8) = pack8(f0, f1);
    return;
  }
  if (blockIdx.x == 3131) {  // zero both gacc buffers (4096 floats)
    float4 z = {0.f, 0.f, 0.f, 0.f};
    for (int i = 0; i < 4; i++)
      ((float4*)gaccz)[threadIdx.x * 4 + i] = z;
    return;
  }
  int tid = (blockIdx.x - 3125) * 256 + threadIdx.x;
  if (tid < 1024) {
    int l = tid & 63, st = tid >> 6;
    int s = st >> 2, t = st & 3;
    int quad = l >> 4, n16 = l & 15;
    for (int j = 0; j < 8; j++) {
      int k = 32 * s + quad * 8 + j, c = 16 * t + n16;
      float w = (s < 2) ? (W1[k * 64 + c] - W1[(k + 64) * 64 + c])
                        : W1[k * 64 + c];
      wp1[tid * 8 + j] = bf16b(w);
    }
  } else if (tid < 1536) {
    int e = tid - 1024;
    int l = e & 63, st = e >> 6;
    int s = st >> 2, t = st & 3;
    int quad = l >> 4, n16 = l & 15;
    for (int j = 0; j < 8; j++) {
      int k = 32 * s + quad * 8 + j, c = 16 * t + n16;
      wp2[e * 8 + j] = bf16b(W2[k * 64 + c]);
    }
  }
}

// ---- stats helpers ---------------------------------------------------------
static __device__ __forceinline__ void stat_acc(const f32x4 acc[4], float sacc[4],
                                                float qacc[4]) {
#pragma unroll
  for (int t = 0; t < 4; t++) {
    sacc[t] += (acc[t][0] + acc[t][1]) + (acc[t][2] + acc[t][3]);
    qacc[t] = fmaf(acc[t][0], acc[t][0],
              fmaf(acc[t][1], acc[t][1],
              fmaf(acc[t][2], acc[t][2],
              fmaf(acc[t][3], acc[t][3], qacc[t]))));
  }
}

static __device__ __forceinline__ void stat_flush(float sacc[4], float qacc[4],
                                                  int quad, int n16, float* lstat) {
#pragma unroll
  for (int t = 0; t < 4; t++) {
    float s = sacc[t], q = qacc[t];
    s += __shfl_xor(s, 16); s += __shfl_xor(s, 32);
    q += __shfl_xor(q, 16); q += __shfl_xor(q, 32);
    if (quad == 0) {
      atomicAdd(&lstat[16 * t + n16], s);
      atomicAdd(&lstat[64 + 16 * t + n16], q);
    }
  }
}

// folded BN finalize: per-block recompute of bn coeffs from the 16-slot gacc
static __device__ __forceinline__ void bn_finalize(const float* __restrict__ gacc,
                                                   const float* __restrict__ g,
                                                   const float* __restrict__ be,
                                                   float* lbn, int tid) {
  if (tid < 64) {
    float s = 0.f, q = 0.f;
#pragma unroll
    for (int i = 0; i < GSLOTS; i++) {
      s += gacc[i * 128 + tid];
      q += gacc[i * 128 + 64 + tid];
    }
    float mean = s * (1.0f / E_EDGES);
    float var = q * (1.0f / E_EDGES) - mean * mean;  // biased, matches ref
    float rstd = rsqrtf(var + BN_EPS);
    float a = g[tid] * rstd;
    lbn[tid] = a;
    lbn[64 + tid] = be[tid] - mean * a;  // bn(v) = v*a + b
  }
}

// shared-xi: wave0 computes Y = Xi_block @ Wd (16 nodes x 64 ch) into yt
static __device__ __forceinline__ void compute_y(const short* xit, const short* wfl,
                                                 float* yt, int l, int quad, int n16) {
  bf16x8 a0 = *(const bf16x8*)(&xit[n16 * 64 + quad * 8]);        // A[m=n16][k0]
  bf16x8 a1 = *(const bf16x8*)(&xit[n16 * 64 + 32 + quad * 8]);   // A[m=n16][k1]
  const bf16x8* wf = (const bf16x8*)wfl;
#pragma unroll
  for (int t = 0; t < 4; t++) {
    f32x4 y = {0.f, 0.f, 0.f, 0.f};
    y = MFMA(a0, wf[(0 + t) * 64 + l], y);
    y = MFMA(a1, wf[(4 + t) * 64 + l], y);
#pragma unroll
    for (int r = 0; r < 4; r++)
      yt[(quad * 4 + r) * 64 + 16 * t + n16] = y[r];  // yt[node][channel]
  }
}

// ---- pass 1: 4-nodes-per-wave gather + xj-GEMM1 + shared-xi + stats1 -------
__global__ __launch_bounds__(256, 4) void k_pass1(const short* __restrict__ xb,
                                                  const int* __restrict__ ecol,
                                                  const bf16x8* __restrict__ wp1,
                                                  float* __restrict__ gacc) {
  __shared__ float lstat[128];
  __shared__ float yt[1024];                    // Y = Xi@Wd (4 KB)
  __shared__ int eblk[256];
  __shared__ __align__(16) short xit[1024];     // 16 xi rows (2 KB)
  __shared__ __align__(16) short wfl[8192];     // W1 B-frags (16 KB)
  int tid = threadIdx.x;
  if (tid < 128) lstat[tid] = 0.f;
  int nb = blockIdx.x * 16;
  eblk[tid] = ecol[nb * KE + tid];              // 256 indices, coalesced
  if (tid < 128)
    *(bf16x8*)(&xit[tid * 8]) = ((const bf16x8*)(xb + (size_t)nb * 64))[tid];
#pragma unroll
  for (int r = 0; r < 4; r++)                   // 16 KB W1 frags -> LDS
    ((bf16x8*)wfl)[r * 256 + tid] = wp1[r * 256 + tid];
  __syncthreads();
  int wave = tid >> 6, l = tid & 63, quad = l >> 4, n16 = l & 15;
  const bf16x8* wf = (const bf16x8*)wfl;
  // all 8 gather loads up-front (issued before the Y barrier; no dependency)
  bf16x8 j0[4], j1[4];
#pragma unroll
  for (int v = 0; v < 4; v++) {
    int idx = eblk[(wave * 4 + v) * 16 + n16];
    const short* pj = xb + (size_t)idx * 64 + quad * 8;
    j0[v] = *(const bf16x8*)pj;
    j1[v] = *(const bf16x8*)(pj + 32);
  }
  if (wave == 0) compute_y(xit, wfl, yt, l, quad, n16);
  __syncthreads();
  float sacc[4] = {0.f, 0.f, 0.f, 0.f}, qacc[4] = {0.f, 0.f, 0.f, 0.f};
#pragma unroll
  for (int v = 0; v < 4; v++) {
    int p = wave * 4 + v;
    f32x4 acc[4];
#pragma unroll
    for (int t = 0; t < 4; t++) {
      float yv = yt[p * 64 + 16 * t + n16];     // broadcast: same for all rows
      f32x4 a = {yv, yv, yv, yv};
      a = MFMA(j0[v], wf[(8 + t) * 64 + l], a);
      a = MFMA(j1[v], wf[(12 + t) * 64 + l], a);
      acc[t] = a;
    }
    stat_acc(acc, sacc, qacc);
  }
  stat_flush(sacc, qacc, quad, n16, lstat);
  __syncthreads();
  if (tid < 128)
    atomicAdd(&gacc[(blockIdx.x & (GSLOTS - 1)) * 128 + tid], lstat[tid]);
}

// ---- pass 2: gather + xj-GEMM1 + shared-xi + BN1/ReLU + GEMM2 + stats2 + minmax
__global__ __launch_bounds__(256, 4) void k_pass2(const short* __restrict__ xb,
                                                  const int* __restrict__ ecol,
                                                  const bf16x8* __restrict__ wp1,
                                                  const bf16x8* __restrict__ wp2,
                                                  const float* __restrict__ gacc1,
                                                  const float* __restrict__ g1,
                                                  const float* __restrict__ be1,
                                                  float* __restrict__ gacc,
                                                  short* __restrict__ hmax,
                                                  short* __restrict__ hmin) {
  __shared__ float lstat[128];
  __shared__ float lbn[128];
  __shared__ float yt[1024];
  __shared__ int eblk[256];
  __shared__ __align__(16) short xit[1024];
  __shared__ __align__(16) short wfl[8192];          // W1 B-frags (16 KB)
  __shared__ __align__(16) short tiles[4][16 * 72];  // per-wave D->A transpose
  int tid = threadIdx.x;
  if (tid < 128) lstat[tid] = 0.f;
  bn_finalize(gacc1, g1, be1, lbn, tid);             // folded finalize1
  int nb = blockIdx.x * 16;
  eblk[tid] = ecol[nb * KE + tid];
  if (tid < 128)
    *(bf16x8*)(&xit[tid * 8]) = ((const bf16x8*)(xb + (size_t)nb * 64))[tid];
#pragma unroll
  for (int r = 0; r < 4; r++)
    ((bf16x8*)wfl)[r * 256 + tid] = wp1[r * 256 + tid];
  __syncthreads();
  int wave = tid >> 6, l = tid & 63, quad = l >> 4, n16 = l & 15;
  const bf16x8* wf = (const bf16x8*)wfl;
  bf16x8 wf2[8];
#pragma unroll
  for (int u = 0; u < 8; u++) wf2[u] = wp2[u * 64 + l];
  float a1c[4], b1c[4];
#pragma unroll
  for (int t = 0; t < 4; t++) {
    a1c[t] = lbn[16 * t + n16];
    b1c[t] = lbn[64 + 16 * t + n16];
  }
  bf16x8 j0[4], j1[4];
#pragma unroll
  for (int v = 0; v < 4; v++) {
    int idx = eblk[(wave * 4 + v) * 16 + n16];
    const short* pj = xb + (size_t)idx * 64 + quad * 8;
    j0[v] = *(const bf16x8*)pj;
    j1[v] = *(const bf16x8*)(pj + 32);
  }
  if (wave == 0) compute_y(xit, wfl, yt, l, quad, n16);
  __syncthreads();
  float sacc[4] = {0.f, 0.f, 0.f, 0.f}, qacc[4] = {0.f, 0.f, 0.f, 0.f};
  short* myt = &tiles[wave][0];
#pragma unroll
  for (int v = 0; v < 4; v++) {
    int p = wave * 4 + v;
    f32x4 acc1[4];
#pragma unroll
    for (int t = 0; t < 4; t++) {
      float yv = yt[p * 64 + 16 * t + n16];
      f32x4 a = {yv, yv, yv, yv};
      a = MFMA(j0[v], wf[(8 + t) * 64 + l], a);
      a = MFMA(j1[v], wf[(12 + t) * 64 + l], a);
      acc1[t] = a;
    }
    // BN1 + ReLU, D-layout -> row-major bf16 tile (per-wave, no barrier)
#pragma unroll
    for (int t = 0; t < 4; t++) {
      int c = 16 * t + n16;
#pragma unroll
      for (int r = 0; r < 4; r++) {
        float h = fmaxf(fmaf(acc1[t][r], a1c[t], b1c[t]), 0.f);
        myt[(quad * 4 + r) * 72 + c] = bf16b(h);
      }
    }
    bf16x8 f0 = *(bf16x8*)(myt + n16 * 72 + quad * 8);
    bf16x8 f1 = *(bf16x8*)(myt + n16 * 72 + 32 + quad * 8);
    f32x4 acc2[4];
#pragma unroll
    for (int t = 0; t < 4; t++) {
      f32x4 a = {0.f, 0.f, 0.f, 0.f};
      a = MFMA(f0, wf2[0 + t], a);
      a = MFMA(f1, wf2[4 + t], a);
      acc2[t] = a;
    }
    stat_acc(acc2, sacc, qacc);
    // per-node, per-channel max & min of h2_pre over the 16 edges
    float vmx[4], vmn[4];
#pragma unroll
    for (int t = 0; t < 4; t++) {
      float mx = fmaxf(fmaxf(acc2[t][0], acc2[t][1]), fmaxf(acc2[t][2], acc2[t][3]));
      float mn = fminf(fminf(acc2[t][0], acc2[t][1]), fminf(acc2[t][2], acc2[t][3]));
      mx = fmaxf(mx, __shfl_xor(mx, 16)); mx = fmaxf(mx, __shfl_xor(mx, 32));
      mn = fminf(mn, __shfl_xor(mn, 16)); mn = fminf(mn, __shfl_xor(mn, 32));
      vmx[t] = mx; vmn[t] = mn;
    }
    int n = nb + p;
    float ox = (quad == 0) ? vmx[0] : (quad == 1) ? vmx[1] : (quad == 2) ? vmx[2] : vmx[3];
    float on = (quad == 0) ? vmn[0] : (quad == 1) ? vmn[1] : (quad == 2) ? vmn[2] : vmn[3];
    hmax[(size_t)n * 64 + l] = bf16b(ox);  // lane l == channel l: coalesced
    hmin[(size_t)n * 64 + l] = bf16b(on);
  }
  stat_flush(sacc, qacc, quad, n16, lstat);
  __syncthreads();
  if (tid < 128)
    atomicAdd(&gacc[(blockIdx.x & (GSLOTS - 1)) * 128 + tid], lstat[tid]);
}

// ---- pass 3: folded finalize2 + elementwise BN2/ReLU + min/max select ------
// max_m relu(a*h+b) = relu(a>=0 ? a*hmax+b : a*hmin+b)  (affine+relu monotone)
__global__ __launch_bounds__(256) void k_pass3(const short* __restrict__ hmax,
                                               const short* __restrict__ hmin,
                                               const float* __restrict__ gacc2,
                                               const float* __restrict__ g2,
                                               const float* __restrict__ be2,
                                               float* __restrict__ out) {
  __shared__ float lbn[128];
  int tid = threadIdx.x;
  bn_finalize(gacc2, g2, be2, lbn, tid);  // folded finalize2
  __syncthreads();
  int g = blockIdx.x * 256 + tid;  // 1.6M threads, 4 channels each
  int base = g * 4;
  int c4 = base & 63;
  short4 mx4 = *(const short4*)(hmax + base);
  short4 mn4 = *(const short4*)(hmin + base);
  float4 a4 = *(const float4*)(&lbn[c4]);
  float4 b4 = *(const float4*)(&lbn[64 + c4]);
  float4 o;
  o.x = fmaxf(a4.x >= 0.f ? fmaf(a4.x, bf2f(mx4.x), b4.x) : fmaf(a4.x, bf2f(mn4.x), b4.x), 0.f);
  o.y = fmaxf(a4.y >= 0.f ? fmaf(a4.y, bf2f(mx4.y), b4.y) : fmaf(a4.y, bf2f(mn4.y), b4.y), 0.f);
  o.z = fmaxf(a4.z >= 0.f ? fmaf(a4.z, bf2f(mx4.z), b4.z) : fmaf(a4.z, bf2f(mn4.z), b4.z), 0.f);
  o.w = fmaxf(a4.w >= 0.f ? fmaf(a4.w, bf2f(mx4.w), b4.w) : fmaf(a4.w, bf2f(mn4.w), b4.w), 0.f);
  *(float4*)(out + base) = o;
}

extern "C" void kernel_launch(void* const* d_in, const int* in_sizes, int n_in,
                              void* d_out, int out_size, void* d_ws, size_t ws_size,
                              hipStream_t stream) {
  const float* x   = (const float*)d_in[0];
  // d_in[1] = edge_row: structurally repeat(arange(N),16), unused
  const int*   ec  = (const int*)d_in[2];
  const float* W1  = (const float*)d_in[3];
  // d_in[4] = b1: cancels in BN, unused
  const float* g1  = (const float*)d_in[5];
  const float* be1 = (const float*)d_in[6];
  const float* W2  = (const float*)d_in[7];
  // d_in[8] = b2: cancels in BN, unused
  const float* g2  = (const float*)d_in[9];
  const float* be2 = (const float*)d_in[10];
  float* out = (float*)d_out;

  char* ws = (char*)d_ws;
  bf16x8* wp1  = (bf16x8*)(ws);                 // 16 KB packed W1 (split)
  bf16x8* wp2  = (bf16x8*)(ws + 16384);         // 8 KB packed W2
  float* gacc1 = (float*)(ws + 24576);          // 16 slots x 128 = 8 KB
  float* gacc2 = (float*)(ws + 32768);          // 8 KB
  short* xb    = (short*)(ws + 98304);          // x in bf16: 12.8 MB
  short* hmax  = (short*)(ws + 98304 + 12800000);         // 12.8 MB
  short* hmin  = (short*)(ws + 98304 + 2 * 12800000);     // 12.8 MB

  hipLaunchKernelGGL(k_prep, dim3(3132), dim3(256), 0, stream, x, xb,
                     W1, W2, (short*)wp1, (short*)wp2, gacc1);
  hipLaunchKernelGGL(k_pass1, dim3(NCHUNK), dim3(256), 0, stream,
                     xb, ec, wp1, gacc1);
  hipLaunchKernelGGL(k_pass2, dim3(NCHUNK), dim3(256), 0, stream,
                     xb, ec, wp1, wp2, gacc1, g1, be1, gacc2, hmax, hmin);
  hipLaunchKernelGGL(k_pass3, dim3(6250), dim3(256), 0, stream,
                     hmax, hmin, gacc2, g2, be2, out);
}